// Round 2
// baseline (687.839 us; speedup 1.0000x reference)
//
#include <hip/hip_runtime.h>

#define H       4096
#define RANK    16
#define NROWS   16384      // BATCH * SEQ
#define RPB     4          // rows per block
#define TPB     256
#define TWO_OVER_PI 0.63661977236758134f

typedef float f32x4 __attribute__((ext_vector_type(4)));   // nontemporal-store-compatible

// ---- prep: repack int32-stored int8 A/B into true int8 in workspace ----
__global__ __launch_bounds__(256) void pack_ab(const int* __restrict__ A32,
                                               const int* __restrict__ B32,
                                               unsigned int* __restrict__ A8,
                                               unsigned int* __restrict__ B8) {
    int i = blockIdx.x * 256 + threadIdx.x;      // 0..16383, packs 4 elems each
    int4 a = ((const int4*)A32)[i];
    int4 b = ((const int4*)B32)[i];
    unsigned int pa = ((unsigned)(a.x & 0xff))        | ((unsigned)(a.y & 0xff) << 8) |
                      ((unsigned)(a.z & 0xff) << 16)  | ((unsigned)(a.w & 0xff) << 24);
    unsigned int pb = ((unsigned)(b.x & 0xff))        | ((unsigned)(b.y & 0xff) << 8) |
                      ((unsigned)(b.z & 0xff) << 16)  | ((unsigned)(b.w & 0xff) << 24);
    A8[i] = pa;
    B8[i] = pb;
}

// ---- fused: h = x@A (block-local reduce), out = x + 2*sin((h@B)*2/pi) ----
__global__ __launch_bounds__(TPB, 2) void pilora_fused(
    const float* __restrict__ x,
    const unsigned char* __restrict__ A8,   // [H][16] int8
    const unsigned char* __restrict__ B8,   // [16][H] int8
    const float* __restrict__ sA,           // [16]
    const float* __restrict__ sB,           // [H]
    float* __restrict__ out)
{
    const int t    = threadIdx.x;
    const int row0 = blockIdx.x * RPB;

    __shared__ float red[16][257];   // rank-major partials, +1 pad
    __shared__ float part[16][17];
    __shared__ float hsh[RPB][RANK];

    // ---- load this block's 4 rows of x into registers (coalesced float4) ----
    // thread t owns cols {c*1024 + 4t .. +3} for c in 0..3
    float xr[RPB][16];
    const float4* x4 = (const float4*)x;
    #pragma unroll
    for (int rr = 0; rr < RPB; ++rr) {
        #pragma unroll
        for (int c = 0; c < 4; ++c) {
            float4 v = x4[(row0 + rr) * 1024 + c * 256 + t];
            xr[rr][c*4+0] = v.x; xr[rr][c*4+1] = v.y;
            xr[rr][c*4+2] = v.z; xr[rr][c*4+3] = v.w;
        }
    }

    // ---- phase 1: per-thread partial h over its 16 columns ----
    float acc[RPB][RANK];
    #pragma unroll
    for (int rr = 0; rr < RPB; ++rr)
        #pragma unroll
        for (int r = 0; r < RANK; ++r) acc[rr][r] = 0.0f;

    const int4* A16 = (const int4*)A8;   // one int4 = one column's 16 int8 coeffs
    #pragma unroll
    for (int c = 0; c < 4; ++c) {
        #pragma unroll
        for (int e = 0; e < 4; ++e) {
            int col = c * 1024 + t * 4 + e;
            int4 q = A16[col];
            float a[RANK];
            int w0 = q.x, w1 = q.y, w2 = q.z, w3 = q.w;
            #pragma unroll
            for (int b = 0; b < 4; ++b) {
                a[0  + b] = (float)((signed char)(w0 >> (8*b)));
                a[4  + b] = (float)((signed char)(w1 >> (8*b)));
                a[8  + b] = (float)((signed char)(w2 >> (8*b)));
                a[12 + b] = (float)((signed char)(w3 >> (8*b)));
            }
            #pragma unroll
            for (int rr = 0; rr < RPB; ++rr) {
                float xe = xr[rr][c*4 + e];
                #pragma unroll
                for (int r = 0; r < RANK; ++r)
                    acc[rr][r] += xe * a[r];
            }
        }
    }

    // ---- block reduction: h[rr][r] = sA[r] * sum_t acc[rr][r] ----
    #pragma unroll 1
    for (int rr = 0; rr < RPB; ++rr) {
        if (rr) __syncthreads();
        #pragma unroll
        for (int r = 0; r < RANK; ++r) red[r][t] = acc[rr][r];
        __syncthreads();
        {
            int r = t & 15, g = t >> 4;          // 16 groups of 16 threads
            float s = 0.0f;
            #pragma unroll
            for (int k = 0; k < 16; ++k) s += red[r][g*16 + k];
            part[r][g] = s;
        }
        __syncthreads();
        if (t < 16) {
            float s = 0.0f;
            #pragma unroll
            for (int g = 0; g < 16; ++g) s += part[t][g];
            hsh[rr][t] = s * sA[t];
        }
    }
    __syncthreads();

    // ---- phase 2: g2[row][col] = sum_r h[row][r] * Bq[r][col] ----
    float g2[RPB][16];
    #pragma unroll
    for (int rr = 0; rr < RPB; ++rr)
        #pragma unroll
        for (int j = 0; j < 16; ++j) g2[rr][j] = 0.0f;

    const int* B4 = (const int*)B8;
    #pragma unroll
    for (int r = 0; r < RANK; ++r) {
        float h0 = hsh[0][r], h1 = hsh[1][r], h2 = hsh[2][r], h3 = hsh[3][r];
        #pragma unroll
        for (int c = 0; c < 4; ++c) {
            int w = B4[r*1024 + c*256 + t];      // 4 int8 of B row r at my cols
            #pragma unroll
            for (int b = 0; b < 4; ++b) {
                float bv = (float)((signed char)(w >> (8*b)));
                g2[0][c*4+b] += h0 * bv;
                g2[1][c*4+b] += h1 * bv;
                g2[2][c*4+b] += h2 * bv;
                g2[3][c*4+b] += h3 * bv;
            }
        }
    }

    // ---- epilogue: out = x + 2*sin(g2 * sB * 2/pi), nontemporal stores ----
    const float4* sB4 = (const float4*)sB;
    f32x4* o4 = (f32x4*)out;
    #pragma unroll
    for (int c = 0; c < 4; ++c) {
        float4 sb = sB4[c*256 + t];
        float k0 = sb.x * TWO_OVER_PI;
        float k1 = sb.y * TWO_OVER_PI;
        float k2 = sb.z * TWO_OVER_PI;
        float k3 = sb.w * TWO_OVER_PI;
        #pragma unroll
        for (int rr = 0; rr < RPB; ++rr) {
            f32x4 o;
            o.x = xr[rr][c*4+0] + 2.0f * __sinf(g2[rr][c*4+0] * k0);
            o.y = xr[rr][c*4+1] + 2.0f * __sinf(g2[rr][c*4+1] * k1);
            o.z = xr[rr][c*4+2] + 2.0f * __sinf(g2[rr][c*4+2] * k2);
            o.w = xr[rr][c*4+3] + 2.0f * __sinf(g2[rr][c*4+3] * k3);
            __builtin_nontemporal_store(o, &o4[(row0 + rr) * 1024 + c * 256 + t]);
        }
    }
}

extern "C" void kernel_launch(void* const* d_in, const int* in_sizes, int n_in,
                              void* d_out, int out_size, void* d_ws, size_t ws_size,
                              hipStream_t stream) {
    const float* x   = (const float*)d_in[0];
    const int*   A32 = (const int*)d_in[1];
    const int*   B32 = (const int*)d_in[2];
    const float* sA  = (const float*)d_in[3];
    const float* sB  = (const float*)d_in[4];
    float*       out = (float*)d_out;

    unsigned int* A8 = (unsigned int*)d_ws;               // 64 KB
    unsigned int* B8 = A8 + (H * RANK / 4);               // 64 KB

    pack_ab<<<(H * RANK / 4) / 256, 256, 0, stream>>>(A32, B32, A8, B8);
    pilora_fused<<<NROWS / RPB, TPB, 0, stream>>>(
        x, (const unsigned char*)A8, (const unsigned char*)B8, sA, sB, out);
}